// Round 2
// baseline (412.073 us; speedup 1.0000x reference)
//
#include <hip/hip_runtime.h>
#include <math.h>

#define DIM 256
#define OUT 8
#define EPS 1e-5f
#define CHUNK 32                 // dims per K-chunk
#define NCHUNK (DIM / CHUNK)     // 8
// per wave: 64 tokens, 8 KB LDS region; block = 4 waves = 256 tokens, 32 KB LDS

__global__ __launch_bounds__(256) void ffn_kernel(
    const float* __restrict__ x,
    const float* __restrict__ W1,
    const float* __restrict__ b1,
    const float* __restrict__ W2,
    const float* __restrict__ b2,
    const float* __restrict__ gamma,
    const float* __restrict__ beta,
    float* __restrict__ out,
    int n_tokens)
{
    const int tid  = threadIdx.x;
    const int wid  = tid >> 6;
    const int lane = tid & 63;

    // wave's first token
    const long wave_tok = (long)blockIdx.x * 256 + wid * 64;
    if (wave_tok >= n_tokens) return;
    const float* xw = x + wave_tok * DIM;

    // 4 waves x 2048 floats (8 KB) each; wave-private -> no __syncthreads anywhere.
    // Layout per wave: L[c][t][k] word = c*256 + t*4 + k  (c: dim-group of 4, t: token 0..63)
    __shared__ float lds[4 * 2048];
    float* L = lds + (wid << 11);

    const int r_off = lane >> 3;   // token sub-row this lane stages (0..7, +8*i)
    const int c_ld  = lane & 7;    // dim-group this lane stages

    float acc[OUT];
    #pragma unroll
    for (int o = 0; o < OUT; ++o) acc[o] = b1[o];

    // prefetch chunk 0: coalesced — lanes 0..7 cover 128 B contiguous per token row
    float4 stage[8];
    #pragma unroll
    for (int i = 0; i < 8; ++i) {
        int r = i * 8 + r_off;
        stage[i] = *(const float4*)(xw + r * DIM + c_ld * 4);
    }

    for (int ch = 0; ch < NCHUNK; ++ch) {
        // write staged chunk to LDS (transposed-interleaved-4; conflict-free: 8 bank-groups x 8 lanes)
        #pragma unroll
        for (int i = 0; i < 8; ++i) {
            int r = i * 8 + r_off;
            *(float4*)&L[c_ld * 256 + r * 4] = stage[i];
        }
        // prefetch next chunk while we compute this one (DS ops are in-order per wave,
        // so these global loads overlap the ds_read/FMA below)
        if (ch + 1 < NCHUNK) {
            #pragma unroll
            for (int i = 0; i < 8; ++i) {
                int r = i * 8 + r_off;
                stage[i] = *(const float4*)(xw + r * DIM + (ch + 1) * CHUNK + c_ld * 4);
            }
        }
        // compute: thread == token `lane` of this wave; reads conflict-free (lane*4 mod 32)
        #pragma unroll
        for (int c = 0; c < 8; ++c) {
            float4 xv = *(const float4*)&L[c * 256 + lane * 4];
            #pragma unroll
            for (int o = 0; o < OUT; ++o) {
                // wave-uniform W1 index -> scalar loads on the SMEM pipe
                float4 w = *(const float4*)&W1[o * DIM + ch * CHUNK + c * 4];
                acc[o] = fmaf(xv.x, w.x, acc[o]);
                acc[o] = fmaf(xv.y, w.y, acc[o]);
                acc[o] = fmaf(xv.z, w.z, acc[o]);
                acc[o] = fmaf(xv.w, w.w, acc[o]);
            }
        }
    }

    // ---- epilogue (unchanged from passing R1) ----
    // exact GELU (erf), matches jax.nn.gelu(approximate=False)
    float g[OUT];
    #pragma unroll
    for (int o = 0; o < OUT; ++o) {
        float h = acc[o];
        g[o] = 0.5f * h * (1.0f + erff(h * 0.70710678118654752f));
    }

    float h2[OUT];
    float sum = 0.f;
    #pragma unroll
    for (int p = 0; p < OUT; ++p) {
        float a = b2[p];
        #pragma unroll
        for (int o = 0; o < OUT; ++o)
            a = fmaf(W2[p * OUT + o], g[o], a);
        h2[p] = a;
        sum += a;
    }

    float mu = sum * (1.0f / OUT);
    float vs = 0.f;
    #pragma unroll
    for (int p = 0; p < OUT; ++p) {
        float d = h2[p] - mu;
        vs = fmaf(d, d, vs);
    }
    float rs = rsqrtf(vs * (1.0f / OUT) + EPS);

    float r[OUT];
    #pragma unroll
    for (int p = 0; p < OUT; ++p)
        r[p] = (h2[p] - mu) * rs * gamma[p] + beta[p];

    const long t = wave_tok + lane;
    float4* outv = (float4*)(out + t * OUT);
    outv[0] = make_float4(r[0], r[1], r[2], r[3]);
    outv[1] = make_float4(r[4], r[5], r[6], r[7]);
}

extern "C" void kernel_launch(void* const* d_in, const int* in_sizes, int n_in,
                              void* d_out, int out_size, void* d_ws, size_t ws_size,
                              hipStream_t stream) {
    const float* x     = (const float*)d_in[0];
    const float* W1    = (const float*)d_in[1];
    const float* b1    = (const float*)d_in[2];
    const float* W2    = (const float*)d_in[3];
    const float* b2    = (const float*)d_in[4];
    const float* gamma = (const float*)d_in[5];
    const float* beta  = (const float*)d_in[6];
    float* out = (float*)d_out;

    int n_tokens = in_sizes[0] / DIM;            // 262144
    int grid = (n_tokens + 255) / 256;           // 1024 blocks x 256 tokens
    ffn_kernel<<<grid, 256, 0, stream>>>(x, W1, b1, W2, b2, gamma, beta, out, n_tokens);
}

// Round 3
// 378.754 us; speedup vs baseline: 1.0880x; 1.0880x over previous
//
#include <hip/hip_runtime.h>
#include <math.h>

#define DIM 256
#define OUT 8
#define EPS 1e-5f

// One wave = 64 tokens. Lane l permanently holds W1[o][4l..4l+3] (32 VGPRs),
// so the main loop is: 1 fully-coalesced 1KB x-row load per token + 32 FMAs +
// a fused 4-token cross-lane butterfly reduction. No LDS, no W1 memory traffic.
__global__ __launch_bounds__(256) void ffn_kernel(
    const float* __restrict__ x,
    const float* __restrict__ W1,
    const float* __restrict__ b1,
    const float* __restrict__ W2,
    const float* __restrict__ b2,
    const float* __restrict__ gamma,
    const float* __restrict__ beta,
    float* __restrict__ out)
{
    const int tid  = threadIdx.x;
    const int wid  = tid >> 6;
    const int lane = tid & 63;

    const long wave_tok = (long)blockIdx.x * 256 + (long)wid * 64;
    const float4* xr = (const float4*)(x + wave_tok * DIM);  // token t: xr[t*64 + lane]

    // preload W1 rows into registers: lane l gets dims 4l..4l+3 of each output row
    float4 w1r[OUT];
    #pragma unroll
    for (int o = 0; o < OUT; ++o)
        w1r[o] = ((const float4*)(W1 + o * DIM))[lane];

    float h[OUT];   // lane l ends up owning token (wave_tok + l)'s GEMM1 result

    for (int g = 0; g < 16; ++g) {          // 16 groups x 4 tokens
        // 4 coalesced row loads (1 KB each, single contiguous segment)
        float4 xv0 = xr[(g * 4 + 0) * 64 + lane];
        float4 xv1 = xr[(g * 4 + 1) * 64 + lane];
        float4 xv2 = xr[(g * 4 + 2) * 64 + lane];
        float4 xv3 = xr[(g * 4 + 3) * 64 + lane];

        // per-lane partials, tokens 0/1 first (keeps register pressure low)
        float m01[OUT], m23[OUT];
        {
            float s0[OUT], s1[OUT];
            #pragma unroll
            for (int o = 0; o < OUT; ++o) {
                float4 w = w1r[o];
                s0[o] = fmaf(xv0.x, w.x, fmaf(xv0.y, w.y, fmaf(xv0.z, w.z, xv0.w * w.w)));
                s1[o] = fmaf(xv1.x, w.x, fmaf(xv1.y, w.y, fmaf(xv1.z, w.z, xv1.w * w.w)));
            }
            #pragma unroll
            for (int o = 0; o < OUT; ++o) {
                s0[o] += __shfl_xor(s0[o], 1, 64);
                s1[o] += __shfl_xor(s1[o], 1, 64);
                m01[o] = (lane & 1) ? s1[o] : s0[o];   // even lanes: tok0, odd: tok1
            }
        }
        {
            float s2[OUT], s3[OUT];
            #pragma unroll
            for (int o = 0; o < OUT; ++o) {
                float4 w = w1r[o];
                s2[o] = fmaf(xv2.x, w.x, fmaf(xv2.y, w.y, fmaf(xv2.z, w.z, xv2.w * w.w)));
                s3[o] = fmaf(xv3.x, w.x, fmaf(xv3.y, w.y, fmaf(xv3.z, w.z, xv3.w * w.w)));
            }
            #pragma unroll
            for (int o = 0; o < OUT; ++o) {
                s2[o] += __shfl_xor(s2[o], 1, 64);
                s3[o] += __shfl_xor(s3[o], 1, 64);
                m23[o] = (lane & 1) ? s3[o] : s2[o];
            }
        }
        // stage 2 separately per pair-stream, then merge by bit1
        float m[OUT];
        #pragma unroll
        for (int o = 0; o < OUT; ++o) {
            m01[o] += __shfl_xor(m01[o], 2, 64);
            m23[o] += __shfl_xor(m23[o], 2, 64);
            m[o] = (lane & 2) ? m23[o] : m01[o];
        }
        // shared stages: xor 4,8,16,32 preserve lane&3 -> streams stay separated
        #pragma unroll
        for (int o = 0; o < OUT; ++o) {
            m[o] += __shfl_xor(m[o], 4, 64);
            m[o] += __shfl_xor(m[o], 8, 64);
            m[o] += __shfl_xor(m[o], 16, 64);
            m[o] += __shfl_xor(m[o], 32, 64);
        }
        // lane l now holds the full sum for token g*4 + (l&3)
        if ((lane >> 2) == g) {
            #pragma unroll
            for (int o = 0; o < OUT; ++o) h[o] = m[o];
        }
    }

    // ---- epilogue: lane l == token wave_tok + l ----
    float gl[OUT];
    #pragma unroll
    for (int o = 0; o < OUT; ++o) {
        float v = h[o] + b1[o];
        gl[o] = 0.5f * v * (1.0f + erff(v * 0.70710678118654752f));
    }

    float h2[OUT];
    float sum = 0.f;
    #pragma unroll
    for (int p = 0; p < OUT; ++p) {
        float a = b2[p];
        #pragma unroll
        for (int o = 0; o < OUT; ++o)
            a = fmaf(W2[p * OUT + o], gl[o], a);
        h2[p] = a;
        sum += a;
    }

    float mu = sum * (1.0f / OUT);
    float vs = 0.f;
    #pragma unroll
    for (int p = 0; p < OUT; ++p) {
        float d = h2[p] - mu;
        vs = fmaf(d, d, vs);
    }
    float rs = rsqrtf(vs * (1.0f / OUT) + EPS);

    float r[OUT];
    #pragma unroll
    for (int p = 0; p < OUT; ++p)
        r[p] = (h2[p] - mu) * rs * gamma[p] + beta[p];

    float4* outv = (float4*)(out + (wave_tok + lane) * OUT);
    outv[0] = make_float4(r[0], r[1], r[2], r[3]);
    outv[1] = make_float4(r[4], r[5], r[6], r[7]);
}

extern "C" void kernel_launch(void* const* d_in, const int* in_sizes, int n_in,
                              void* d_out, int out_size, void* d_ws, size_t ws_size,
                              hipStream_t stream) {
    const float* x     = (const float*)d_in[0];
    const float* W1    = (const float*)d_in[1];
    const float* b1    = (const float*)d_in[2];
    const float* W2    = (const float*)d_in[3];
    const float* b2    = (const float*)d_in[4];
    const float* gamma = (const float*)d_in[5];
    const float* beta  = (const float*)d_in[6];
    float* out = (float*)d_out;

    int n_tokens = in_sizes[0] / DIM;        // 262144, exact multiple of 256
    int grid = n_tokens / 256;               // 1024 blocks, 64 tokens/wave, no guards
    ffn_kernel<<<grid, 256, 0, stream>>>(x, W1, b1, W2, b2, gamma, beta, out);
}

// Round 4
// 374.332 us; speedup vs baseline: 1.1008x; 1.0118x over previous
//
#include <hip/hip_runtime.h>
#include <math.h>

#define DIM 256
#define OUT 8
#define EPS 1e-5f

// One wave = 64 tokens, processed 2 per pass (half-wave each). Lane covers 8
// dims (float4 cols hl and hl+32) of its token for all 8 outputs; weights live
// in 64 VGPRs, loaded once. Reduction = multi-value butterfly over 32 lanes:
// 9 shuffles per 2 tokens (vs 80 per 4 tokens in R3). Results land in a
// wave-private LDS slab, gathered so lane l owns token l for the epilogue.
// No __syncthreads anywhere (wave-private LDS, DS in-order per wave).
__global__ __launch_bounds__(256) void ffn_kernel(
    const float* __restrict__ x,
    const float* __restrict__ W1,
    const float* __restrict__ b1,
    const float* __restrict__ W2,
    const float* __restrict__ b2,
    const float* __restrict__ gamma,
    const float* __restrict__ beta,
    float* __restrict__ out)
{
    const int tid  = threadIdx.x;
    const int wid  = tid >> 6;
    const int lane = tid & 63;
    const int hl   = lane & 31;      // position within half-wave
    const int tpar = lane >> 5;      // which of the pass's 2 tokens this lane serves

    const long wave_tok = (long)blockIdx.x * 256 + (long)wid * 64;
    const float4* xr = (const float4*)(x + wave_tok * DIM);   // token t row: xr + t*64

    // weights once into registers: lane covers float4 cols hl and hl+32
    float4 w0[OUT], w1[OUT];
    #pragma unroll
    for (int o = 0; o < OUT; ++o) {
        const float4* wrow = (const float4*)(W1 + o * DIM);
        w0[o] = wrow[hl];
        w1[o] = wrow[hl + 32];
    }

    __shared__ float hbuf[4 * 64 * OUT];     // 8 KB, wave-private 2 KB slabs
    float* H = hbuf + (wid << 9);

    const bool b4 = (lane & 16) != 0;
    const bool b3 = (lane & 8)  != 0;
    const bool bb2 = (lane & 4) != 0;
    const int  o_own = (lane >> 2) & 7;      // output this lane ends up holding

    for (int g = 0; g < 32; ++g) {
        const int T = 2 * g + tpar;          // local token index
        const float4* row = xr + (long)T * 64;
        float4 xa = row[hl];                 // 512B contiguous per half-wave
        float4 xb = row[hl + 32];

        // partials: two independent even/odd chains per output (pk_fma-friendly)
        float p[OUT];
        #pragma unroll
        for (int o = 0; o < OUT; ++o) {
            float se = fmaf(xa.x, w0[o].x, fmaf(xa.z, w0[o].z,
                       fmaf(xb.x, w1[o].x, xb.z * w1[o].z)));
            float so = fmaf(xa.y, w0[o].y, fmaf(xa.w, w0[o].w,
                       fmaf(xb.y, w1[o].y, xb.w * w1[o].w)));
            p[o] = se + so;
        }

        // stage A (xor 16): 8 -> 4 values/lane. Lanes b4=0 keep outputs 0..3.
        float q[4];
        #pragma unroll
        for (int i = 0; i < 4; ++i) {
            float send = b4 ? p[i]     : p[i + 4];
            float keep = b4 ? p[i + 4] : p[i];
            q[i] = keep + __shfl_xor(send, 16, 64);
        }
        // stage B (xor 8): 4 -> 2
        float q2[2];
        #pragma unroll
        for (int i = 0; i < 2; ++i) {
            float send = b3 ? q[i]     : q[i + 2];
            float keep = b3 ? q[i + 2] : q[i];
            q2[i] = keep + __shfl_xor(send, 8, 64);
        }
        // stage C (xor 4): 2 -> 1, then plain stages finish the 32-lane sum
        float send = bb2 ? q2[0] : q2[1];
        float keep = bb2 ? q2[1] : q2[0];
        float r = keep + __shfl_xor(send, 4, 64);
        r += __shfl_xor(r, 2, 64);
        r += __shfl_xor(r, 1, 64);
        // r = h[o_own] (pre-bias) for token T; one lane per (T,o) writes it.
        // Active lanes write 16 consecutive words -> conflict-free.
        if ((lane & 3) == 0) H[T * OUT + o_own] = r;
    }

    // gather: lane l owns token l
    float4 ha = *(const float4*)&H[lane * OUT];
    float4 hb = *(const float4*)&H[lane * OUT + 4];
    float h[OUT] = {ha.x, ha.y, ha.z, ha.w, hb.x, hb.y, hb.z, hb.w};

    // ---- epilogue: bias + exact-erf GELU + 8x8 GEMM2 + LayerNorm ----
    float gl[OUT];
    #pragma unroll
    for (int o = 0; o < OUT; ++o) {
        float v = h[o] + b1[o];
        gl[o] = 0.5f * v * (1.0f + erff(v * 0.70710678118654752f));
    }

    float h2[OUT];
    float sum = 0.f;
    #pragma unroll
    for (int pp = 0; pp < OUT; ++pp) {
        float a = b2[pp];
        #pragma unroll
        for (int o = 0; o < OUT; ++o)
            a = fmaf(W2[pp * OUT + o], gl[o], a);
        h2[pp] = a;
        sum += a;
    }

    float mu = sum * (1.0f / OUT);
    float vs = 0.f;
    #pragma unroll
    for (int pp = 0; pp < OUT; ++pp) {
        float d = h2[pp] - mu;
        vs = fmaf(d, d, vs);
    }
    float rs = rsqrtf(vs * (1.0f / OUT) + EPS);

    float r[OUT];
    #pragma unroll
    for (int pp = 0; pp < OUT; ++pp)
        r[pp] = (h2[pp] - mu) * rs * gamma[pp] + beta[pp];

    float4* outv = (float4*)(out + (wave_tok + lane) * OUT);
    outv[0] = make_float4(r[0], r[1], r[2], r[3]);
    outv[1] = make_float4(r[4], r[5], r[6], r[7]);
}

extern "C" void kernel_launch(void* const* d_in, const int* in_sizes, int n_in,
                              void* d_out, int out_size, void* d_ws, size_t ws_size,
                              hipStream_t stream) {
    const float* x     = (const float*)d_in[0];
    const float* W1    = (const float*)d_in[1];
    const float* b1    = (const float*)d_in[2];
    const float* W2    = (const float*)d_in[3];
    const float* b2    = (const float*)d_in[4];
    const float* gamma = (const float*)d_in[5];
    const float* beta  = (const float*)d_in[6];
    float* out = (float*)d_out;

    int n_tokens = in_sizes[0] / DIM;        // 262144, exact multiple of 256
    int grid = n_tokens / 256;               // 1024 blocks, 64 tokens/wave, no guards
    ffn_kernel<<<grid, 256, 0, stream>>>(x, W1, b1, W2, b2, gamma, beta, out);
}

// Round 6
// 351.041 us; speedup vs baseline: 1.1739x; 1.0663x over previous
//
#include <hip/hip_runtime.h>
#include <math.h>

#define DIM 256
#define OUT 8
#define EPS 1e-5f

// native vector type: __builtin_nontemporal_load/store rejects HIP_vector_type
// (float4 is a class); clang ext_vector_type works and emits dwordx4 nt.
typedef float vf4 __attribute__((ext_vector_type(4)));

// One wave = 64 tokens, 2 per pass (half-wave each). Lane holds W1 cols
// [4*hl..] and [128+4*hl..] for all 8 outputs in 64 VGPRs (loaded once).
// Per pass: 2 nontemporal coalesced float4 loads/lane + 72 FMA-class ops +
// 9-shuffle multi-value butterfly. Software-pipelined (depth 2) so next-pass
// loads are in flight during the reduction's dependent shuffle chain.
// Wave-private LDS slab regathers h so lane l owns token l for the epilogue.
// No __syncthreads anywhere. __launch_bounds__(256,4): cap VGPR<=128 so all
// 4 blocks/CU stay co-resident (16 waves/CU) for latency hiding.
__global__ __launch_bounds__(256, 4) void ffn_kernel(
    const float* __restrict__ x,
    const float* __restrict__ W1,
    const float* __restrict__ b1,
    const float* __restrict__ W2,
    const float* __restrict__ b2,
    const float* __restrict__ gamma,
    const float* __restrict__ beta,
    float* __restrict__ out)
{
    const int tid  = threadIdx.x;
    const int wid  = tid >> 6;
    const int lane = tid & 63;
    const int hl   = lane & 31;      // position within half-wave
    const int tpar = lane >> 5;      // which of the pass's 2 tokens this lane serves

    const long wave_tok = (long)blockIdx.x * 256 + (long)wid * 64;
    const vf4* xr = (const vf4*)(x + wave_tok * DIM);   // token t row: xr + t*64

    // weights once into registers: lane covers float4 cols hl and hl+32
    vf4 w0[OUT], w1[OUT];
    #pragma unroll
    for (int o = 0; o < OUT; ++o) {
        const vf4* wrow = (const vf4*)(W1 + o * DIM);
        w0[o] = wrow[hl];
        w1[o] = wrow[hl + 32];
    }

    __shared__ float hbuf[4 * 64 * OUT];     // 8 KB, wave-private 2 KB slabs
    float* H = hbuf + (wid << 9);

    const bool b4  = (lane & 16) != 0;
    const bool b3  = (lane & 8)  != 0;
    const bool bb2 = (lane & 4)  != 0;
    const int  o_own = (lane >> 2) & 7;      // output this lane ends up holding

    // pipeline prologue: pass 0 loads (nontemporal: pure stream, no reuse)
    const vf4* row0 = xr + (long)tpar * 64;
    vf4 xa = __builtin_nontemporal_load(&row0[hl]);
    vf4 xb = __builtin_nontemporal_load(&row0[hl + 32]);

    for (int g = 0; g < 32; ++g) {
        vf4 na, nb;
        if (g + 1 < 32) {   // wave-uniform branch (s_cbranch) — no divergence
            const vf4* rown = xr + (long)(2 * (g + 1) + tpar) * 64;
            na = __builtin_nontemporal_load(&rown[hl]);
            nb = __builtin_nontemporal_load(&rown[hl + 32]);
        }

        // partials: two independent even/odd chains per output (pk_fma-friendly)
        float p[OUT];
        #pragma unroll
        for (int o = 0; o < OUT; ++o) {
            float se = fmaf(xa.x, w0[o].x, fmaf(xa.z, w0[o].z,
                       fmaf(xb.x, w1[o].x, xb.z * w1[o].z)));
            float so = fmaf(xa.y, w0[o].y, fmaf(xa.w, w0[o].w,
                       fmaf(xb.y, w1[o].y, xb.w * w1[o].w)));
            p[o] = se + so;
        }

        // stage A (xor 16): 8 -> 4 values/lane
        float q[4];
        #pragma unroll
        for (int i = 0; i < 4; ++i) {
            float send = b4 ? p[i]     : p[i + 4];
            float keep = b4 ? p[i + 4] : p[i];
            q[i] = keep + __shfl_xor(send, 16, 64);
        }
        // stage B (xor 8): 4 -> 2
        float q2[2];
        #pragma unroll
        for (int i = 0; i < 2; ++i) {
            float send = b3 ? q[i]     : q[i + 2];
            float keep = b3 ? q[i + 2] : q[i];
            q2[i] = keep + __shfl_xor(send, 8, 64);
        }
        // stage C (xor 4): 2 -> 1, then plain stages finish the 32-lane sum
        float send = bb2 ? q2[0] : q2[1];
        float keep = bb2 ? q2[1] : q2[0];
        float r = keep + __shfl_xor(send, 4, 64);
        r += __shfl_xor(r, 2, 64);
        r += __shfl_xor(r, 1, 64);
        // r = h[o_own] (pre-bias) for token 2g+tpar; 16 designated lanes write
        // 16 consecutive words -> conflict-free.
        if ((lane & 3) == 0) H[(2 * g + tpar) * OUT + o_own] = r;

        xa = na; xb = nb;
    }

    // gather: lane l owns token l (wave-private LDS, DS in-order per wave)
    vf4 ha = *(const vf4*)&H[lane * OUT];
    vf4 hb = *(const vf4*)&H[lane * OUT + 4];
    float h[OUT] = {ha.x, ha.y, ha.z, ha.w, hb.x, hb.y, hb.z, hb.w};

    // ---- epilogue: bias + exact-erf GELU + 8x8 GEMM2 + LayerNorm ----
    float gl[OUT];
    #pragma unroll
    for (int o = 0; o < OUT; ++o) {
        float v = h[o] + b1[o];
        gl[o] = 0.5f * v * (1.0f + erff(v * 0.70710678118654752f));
    }

    float h2[OUT];
    float sum = 0.f;
    #pragma unroll
    for (int pp = 0; pp < OUT; ++pp) {
        float a = b2[pp];
        #pragma unroll
        for (int o = 0; o < OUT; ++o)
            a = fmaf(W2[pp * OUT + o], gl[o], a);
        h2[pp] = a;
        sum += a;
    }

    float mu = sum * (1.0f / OUT);
    float vs = 0.f;
    #pragma unroll
    for (int pp = 0; pp < OUT; ++pp) {
        float d = h2[pp] - mu;
        vs = fmaf(d, d, vs);
    }
    float rs = rsqrtf(vs * (1.0f / OUT) + EPS);

    float r[OUT];
    #pragma unroll
    for (int pp = 0; pp < OUT; ++pp)
        r[pp] = (h2[pp] - mu) * rs * gamma[pp] + beta[pp];

    vf4* outv = (vf4*)(out + (wave_tok + lane) * OUT);
    vf4 o0 = {r[0], r[1], r[2], r[3]};
    vf4 o1 = {r[4], r[5], r[6], r[7]};
    __builtin_nontemporal_store(o0, &outv[0]);
    __builtin_nontemporal_store(o1, &outv[1]);
}

extern "C" void kernel_launch(void* const* d_in, const int* in_sizes, int n_in,
                              void* d_out, int out_size, void* d_ws, size_t ws_size,
                              hipStream_t stream) {
    const float* x     = (const float*)d_in[0];
    const float* W1    = (const float*)d_in[1];
    const float* b1    = (const float*)d_in[2];
    const float* W2    = (const float*)d_in[3];
    const float* b2    = (const float*)d_in[4];
    const float* gamma = (const float*)d_in[5];
    const float* beta  = (const float*)d_in[6];
    float* out = (float*)d_out;

    int n_tokens = in_sizes[0] / DIM;        // 262144, exact multiple of 256
    int grid = n_tokens / 256;               // 1024 blocks, 64 tokens/wave, no guards
    ffn_kernel<<<grid, 256, 0, stream>>>(x, W1, b1, W2, b2, gamma, beta, out);
}